// Round 8
// baseline (702.236 us; speedup 1.0000x reference)
//
#include <hip/hip_runtime.h>

// ---------------------------------------------------------------------------
// ContrastiveLoss (SCAN t2i cross-attention) on MI355X — round 8.
// N=256x256 pairs, R=36 regions, L=50 words, D=256.
// Barrier-free xattn; softmax/norms computed IN the MFMA fragments.
// r8 vs r6: split by caption length. xattn3 (len<=48, 96% of pairs) uses
// nv=3 compile-time => acc[3][3] etc, total regs ~94 <= 102 cap =>
// __launch_bounds__(256,5) with NO spill => 20 waves/CU. xattn4 (len>48,
// 4%) is the r6 code with early-exit; runs at the 128-reg cap.
// ---------------------------------------------------------------------------

typedef unsigned short u16;
typedef unsigned int u32;

typedef __attribute__((ext_vector_type(8))) __bf16 bf16x8;
typedef __attribute__((ext_vector_type(4))) __bf16 bf16x4;
typedef __attribute__((ext_vector_type(4))) float floatx4;

#define NN 256
#define RR 36
#define LL 50
#define DD 256
#define RP 48    // padded region dim
#define LP 64    // padded word dim (s rows)
#define KP 64    // gram row stride / matvec K
#define ASTR 68  // u16 stride of LDS rows (136B: lo-lanes spread all banks)
#define WROWS 50 // logical LDS rows per wave
#define SLOP 14  // shared overflow rows (reads of rows 50..63 land here)
#define PSTR 264 // u16 stride for prep LDS stage

__device__ __forceinline__ u16 f2bf(float v) {
  u32 u = __builtin_bit_cast(u32, v);
  u += 0x7fffu + ((u >> 16) & 1u);   // RNE (inputs never NaN)
  return (u16)(u >> 16);
}
__device__ __forceinline__ float bflo(u32 w) { return __builtin_bit_cast(float, w << 16); }
__device__ __forceinline__ float bfhi(u32 w) { return __builtin_bit_cast(float, w & 0xffff0000u); }

#define WAVE_SYNC() do { \
  asm volatile("s_waitcnt lgkmcnt(0)" ::: "memory"); \
  __builtin_amdgcn_sched_barrier(0); \
} while (0)

// ---- prep: im -> bf16 padded [48][256]; Gram_i = im im^T -> bf16 [48][64] -
__global__ void prep_im_gram_kernel(const float* __restrict__ im,
                                    u16* __restrict__ im_bf,
                                    u16* __restrict__ gram_bf) {
  __shared__ u16 Lb[RP * PSTR];
  const int i = blockIdx.x;
  const int t = threadIdx.x;
  const float* src = im + (size_t)i * (RR * DD);
  u16* dst = im_bf + (size_t)i * (RP * DD);
  for (int e = t; e < RR * DD; e += 256) {
    int r = e >> 8, d = e & 255;
    u16 b = f2bf(src[e]);
    dst[e] = b;
    Lb[r * PSTR + d] = b;
  }
  for (int e = RR * DD + t; e < RP * DD; e += 256) {
    int r = e >> 8, d = e & 255;
    dst[e] = 0;
    Lb[r * PSTR + d] = 0;
  }
  __syncthreads();
  if (t >= 64) return;   // wave 0 computes Gram via MFMA from LDS
  const int lane = t;
  const int lo = lane & 15, hi = lane >> 4;
  floatx4 acc[3][3];
  #pragma unroll
  for (int m = 0; m < 3; ++m)
    #pragma unroll
    for (int n = 0; n < 3; ++n) acc[m][n] = floatx4{0.f, 0.f, 0.f, 0.f};
  #pragma unroll 2
  for (int kt = 0; kt < 8; ++kt) {
    const int k0 = (kt << 5) + (hi << 3);
    bf16x8 f[3];
    #pragma unroll
    for (int m = 0; m < 3; ++m)
      f[m] = __builtin_bit_cast(bf16x8, *(const uint4*)&Lb[(m * 16 + lo) * PSTR + k0]);
    #pragma unroll
    for (int m = 0; m < 3; ++m)
      #pragma unroll
      for (int n = 0; n < 3; ++n)
        acc[m][n] = __builtin_amdgcn_mfma_f32_16x16x32_bf16(f[m], f[n], acc[m][n], 0, 0, 0);
  }
  u16* g = gram_bf + (size_t)i * (RP * KP);
  #pragma unroll
  for (int m = 0; m < 3; ++m)
    #pragma unroll
    for (int n = 0; n < 3; ++n)
      #pragma unroll
      for (int q = 0; q < 4; ++q)
        g[(m * 16 + hi * 4 + q) * KP + n * 16 + lo] = f2bf(acc[m][n][q]);
  for (int e = lane; e < RP * 16; e += 64) {
    int r = e >> 4, c = e & 15;
    g[r * KP + 48 + c] = 0;
  }
}

// ---- prep: s -> bf16 padded [64][256], cn[j,l] = ||s_j[l]|| ---------------
__global__ void prep_s_kernel(const float* __restrict__ s,
                              u16* __restrict__ s_bf,
                              float* __restrict__ cn) {
  const int j = blockIdx.x;
  const int t = threadIdx.x;
  const float* src = s + (size_t)j * (LL * DD);
  u16* dst = s_bf + (size_t)j * (LP * DD);
  for (int e = t; e < LL * DD; e += 256) dst[e] = f2bf(src[e]);
  for (int e = LL * DD + t; e < LP * DD; e += 256) dst[e] = 0;
  const int l = t >> 2, q = t & 3;
  float acc = 0.f;
  if (l < LL) {
    const float* row = src + l * DD + q * 64;
    #pragma unroll 4
    for (int d = 0; d < 64; ++d) { float v = row[d]; acc = fmaf(v, v, acc); }
  }
  acc += __shfl_xor(acc, 1);
  acc += __shfl_xor(acc, 2);
  if (l < LL && q == 0) cn[j * LL + l] = sqrtf(acc);
}

// ---- xattn3: len<=48 pairs (nv=3 compile-time), 5 blocks/CU ---------------
__global__ __launch_bounds__(256, 5) void xattn3_kernel(
    const u16* __restrict__ im_bf, const u16* __restrict__ s_bf,
    const u16* __restrict__ gram_bf, const float* __restrict__ cn,
    const int* __restrict__ cap, float* __restrict__ scores) {
  __shared__ u16 buf[(4 * WROWS + SLOP) * ASTR];  // 29,104 B

  const int wid  = threadIdx.x >> 6;
  const int lane = threadIdx.x & 63;
  const int lo = lane & 15, hi = lane >> 4;
  const int i = blockIdx.x >> 6;
  const int j = ((blockIdx.x & 63) << 2) | wid;
  const int len = cap[j];
  if (len > 48) return;                 // handled by xattn4

  u16* mybuf = buf + wid * (WROWS * ASTR);

  // zero cols 48..63 of row `lane` (K-pad for matvec kt=1)
  if (lane < WROWS) {
    uint2 z2 = {0u, 0u};
    uint2* zp = (uint2*)&mybuf[lane * ASTR + 48];
    zp[0] = z2; zp[1] = z2; zp[2] = z2; zp[3] = z2;
  }

  // ---- Phase A: G = im_i @ s_j^T (M=48, N=48, K=256) ----------------------
  floatx4 acc[3][3];
  #pragma unroll
  for (int m = 0; m < 3; ++m)
    #pragma unroll
    for (int n = 0; n < 3; ++n) acc[m][n] = floatx4{0.f, 0.f, 0.f, 0.f};

  const u16* imp = im_bf + (size_t)i * (RP * DD);
  const u16* sp  = s_bf  + (size_t)j * (LP * DD);

  #pragma unroll 2
  for (int kt = 0; kt < 8; ++kt) {
    const int k0 = (kt << 5) + (hi << 3);
    bf16x8 af[3], bfr[3];
    #pragma unroll
    for (int m = 0; m < 3; ++m)
      af[m] = __builtin_bit_cast(bf16x8, *(const uint4*)(imp + (m * 16 + lo) * DD + k0));
    #pragma unroll
    for (int n = 0; n < 3; ++n)
      bfr[n] = __builtin_bit_cast(bf16x8, *(const uint4*)(sp + (n * 16 + lo) * DD + k0));
    #pragma unroll
    for (int m = 0; m < 3; ++m)
      #pragma unroll
      for (int n = 0; n < 3; ++n)
        acc[m][n] = __builtin_amdgcn_mfma_f32_16x16x32_bf16(af[m], bfr[n], acc[m][n], 0, 0, 0);
  }

  // ---- In-fragment row norms: ss[m][q] = sum_{valid cols} leaky(G)^2 ------
  float maskf[3];
  #pragma unroll
  for (int n = 0; n < 3; ++n) maskf[n] = (n * 16 + lo < len) ? 1.f : 0.f;

  float ss[3][4];
  #pragma unroll
  for (int m = 0; m < 3; ++m)
    #pragma unroll
    for (int q = 0; q < 4; ++q) ss[m][q] = 0.f;
  #pragma unroll
  for (int m = 0; m < 3; ++m)
    #pragma unroll
    for (int n = 0; n < 3; ++n)
      #pragma unroll
      for (int q = 0; q < 4; ++q) {
        float g = acc[m][n][q];
        float v = fmaxf(g, 0.1f * g);
        ss[m][q] = fmaf(v * v, maskf[n], ss[m][q]);
      }
  #pragma unroll
  for (int off = 1; off < 16; off <<= 1)
    #pragma unroll
    for (int m = 0; m < 3; ++m)
      #pragma unroll
      for (int q = 0; q < 4; ++q)
        ss[m][q] += __shfl_xor(ss[m][q], off);

  float rinv[3][4];
  #pragma unroll
  for (int m = 0; m < 3; ++m)
    #pragma unroll
    for (int q = 0; q < 4; ++q)
      rinv[m][q] = 12.984255368000671f / (sqrtf(ss[m][q]) + 1e-8f); // 9*log2e/(||.||+eps)

  // ---- In-fragment softmax weights + num/psum partials; p -> LDS [l][r] ---
  const bool hiz = (hi == 0);
  float num[3], psum[3];
  #pragma unroll
  for (int n = 0; n < 3; ++n) { num[n] = 0.f; psum[n] = 0.f; }

  #pragma unroll
  for (int m = 0; m < 3; ++m) {
    #pragma unroll
    for (int n = 0; n < 3; ++n) {
      bf16x4 pb;
      #pragma unroll
      for (int q = 0; q < 4; ++q) {
        float g = acc[m][n][q];
        float v = fmaxf(g, 0.1f * g);
        float p = exp2f(v * rinv[m][q]);   // |arg|<=13 for valid cols
        if (m == 2) p = hiz ? p : 0.f;     // zero pad-rows 36..47
        psum[n] += p;
        num[n] = fmaf(p, g, num[n]);
        pb[q] = (__bf16)p;
      }
      *(uint2*)&mybuf[(n * 16 + lo) * ASTR + m * 16 + hi * 4] =
          __builtin_bit_cast(uint2, pb);
    }
  }
  #pragma unroll
  for (int n = 0; n < 3; ++n) {
    num[n]  += __shfl_xor(num[n], 16);  num[n]  += __shfl_xor(num[n], 32);
    psum[n] += __shfl_xor(psum[n], 16); psum[n] += __shfl_xor(psum[n], 32);
  }
  WAVE_SYNC();

  // ---- Gram A-fragments: loaded LATE (acc now dead) -----------------------
  bf16x8 gA[3][2];
  const u16* gp = gram_bf + (size_t)i * (RP * KP);
  #pragma unroll
  for (int m = 0; m < 3; ++m)
    #pragma unroll
    for (int kt = 0; kt < 2; ++kt)
      gA[m][kt] = __builtin_bit_cast(bf16x8,
          *(const uint4*)(gp + (m * 16 + lo) * KP + (kt << 5) + (hi << 3)));

  // ---- matvec: t = Gram_i @ p  (M=48, N=48, K=64 zero-padded) -------------
  floatx4 tac[3][3];
  #pragma unroll
  for (int m = 0; m < 3; ++m)
    #pragma unroll
    for (int n = 0; n < 3; ++n) tac[m][n] = floatx4{0.f, 0.f, 0.f, 0.f};

  #pragma unroll
  for (int kt = 0; kt < 2; ++kt) {
    bf16x8 gB[3];
    #pragma unroll
    for (int n = 0; n < 3; ++n) {
      const uint2* bp = (const uint2*)&mybuf[(n * 16 + lo) * ASTR + (kt << 5) + (hi << 3)];
      uint2 b0 = bp[0], b1 = bp[1];
      uint4 bb; bb.x = b0.x; bb.y = b0.y; bb.z = b1.x; bb.w = b1.y;
      gB[n] = __builtin_bit_cast(bf16x8, bb);
    }
    #pragma unroll
    for (int m = 0; m < 3; ++m)
      #pragma unroll
      for (int n = 0; n < 3; ++n)
        tac[m][n] = __builtin_amdgcn_mfma_f32_16x16x32_bf16(gA[m][kt], gB[n], tac[m][n], 0, 0, 0);
  }

  // ---- wn2 = sum_r p*t per column + finalize + max-free LSE ---------------
  float e4 = 0.f;
  #pragma unroll
  for (int n = 0; n < 3; ++n) {
    float w = 0.f;
    #pragma unroll
    for (int m = 0; m < 3; ++m) {
      uint2 av = *(const uint2*)&mybuf[(n * 16 + lo) * ASTR + m * 16 + hi * 4];
      w = fmaf(bflo(av.x), tac[m][n][0], w);
      w = fmaf(bfhi(av.x), tac[m][n][1], w);
      w = fmaf(bflo(av.y), tac[m][n][2], w);
      w = fmaf(bfhi(av.y), tac[m][n][3], w);
    }
    w += __shfl_xor(w, 16);
    w += __shfl_xor(w, 32);     // all hi-duplicates hold full sum over r
    const int col = n * 16 + lo;
    if (col < len) {
      float inv = __builtin_amdgcn_rcpf(psum[n]);
      float wn2 = fmaxf(w * inv * inv, 0.f);
      float nm  = num[n] * inv;
      float den = fmaxf(sqrtf(wn2) * cn[j * LL + col], 1e-8f);
      float sim = nm * __builtin_amdgcn_rcpf(den);
      e4 += exp2f(sim * 8.656170245333781f);   // 6*log2e; |arg| ~<= 9
    }
  }
  #pragma unroll
  for (int off = 1; off < 64; off <<= 1) e4 += __shfl_xor(e4, off);
  if (lane == 0)
    scores[i * NN + j] = (log2f(e4) - 2.0f) * 0.11552453009332421f; // ln2/6
}

// ---- xattn4: len>48 pairs (~4%), r6 code with early-exit ------------------
__global__ __launch_bounds__(256, 4) void xattn4_kernel(
    const u16* __restrict__ im_bf, const u16* __restrict__ s_bf,
    const u16* __restrict__ gram_bf, const float* __restrict__ cn,
    const int* __restrict__ cap, float* __restrict__ scores) {
  __shared__ u16 buf[(4 * WROWS + SLOP) * ASTR];

  const int wid  = threadIdx.x >> 6;
  const int lane = threadIdx.x & 63;
  const int lo = lane & 15, hi = lane >> 4;
  const int i = blockIdx.x >> 6;
  const int j = ((blockIdx.x & 63) << 2) | wid;
  const int len = cap[j];
  if (len <= 48) return;                // handled by xattn3

  u16* mybuf = buf + wid * (WROWS * ASTR);

  if (lane < WROWS) {
    uint2 z2 = {0u, 0u};
    uint2* zp = (uint2*)&mybuf[lane * ASTR + 48];
    zp[0] = z2; zp[1] = z2; zp[2] = z2; zp[3] = z2;
  }

  floatx4 acc[3][4];
  #pragma unroll
  for (int m = 0; m < 3; ++m)
    #pragma unroll
    for (int n = 0; n < 4; ++n) acc[m][n] = floatx4{0.f, 0.f, 0.f, 0.f};

  const u16* imp = im_bf + (size_t)i * (RP * DD);
  const u16* sp  = s_bf  + (size_t)j * (LP * DD);

  #pragma unroll 2
  for (int kt = 0; kt < 8; ++kt) {
    const int k0 = (kt << 5) + (hi << 3);
    bf16x8 af[3], bfr[4];
    #pragma unroll
    for (int m = 0; m < 3; ++m)
      af[m] = __builtin_bit_cast(bf16x8, *(const uint4*)(imp + (m * 16 + lo) * DD + k0));
    #pragma unroll
    for (int n = 0; n < 4; ++n)
      bfr[n] = __builtin_bit_cast(bf16x8, *(const uint4*)(sp + (n * 16 + lo) * DD + k0));
    #pragma unroll
    for (int m = 0; m < 3; ++m)
      #pragma unroll
      for (int n = 0; n < 4; ++n)
        acc[m][n] = __builtin_amdgcn_mfma_f32_16x16x32_bf16(af[m], bfr[n], acc[m][n], 0, 0, 0);
  }

  float maskf[4];
  #pragma unroll
  for (int n = 0; n < 4; ++n) maskf[n] = (n * 16 + lo < len) ? 1.f : 0.f;

  float ss[3][4];
  #pragma unroll
  for (int m = 0; m < 3; ++m)
    #pragma unroll
    for (int q = 0; q < 4; ++q) ss[m][q] = 0.f;
  #pragma unroll
  for (int m = 0; m < 3; ++m)
    #pragma unroll
    for (int n = 0; n < 4; ++n)
      #pragma unroll
      for (int q = 0; q < 4; ++q) {
        float g = acc[m][n][q];
        float v = fmaxf(g, 0.1f * g);
        ss[m][q] = fmaf(v * v, maskf[n], ss[m][q]);
      }
  #pragma unroll
  for (int off = 1; off < 16; off <<= 1)
    #pragma unroll
    for (int m = 0; m < 3; ++m)
      #pragma unroll
      for (int q = 0; q < 4; ++q)
        ss[m][q] += __shfl_xor(ss[m][q], off);

  float rinv[3][4];
  #pragma unroll
  for (int m = 0; m < 3; ++m)
    #pragma unroll
    for (int q = 0; q < 4; ++q)
      rinv[m][q] = 12.984255368000671f / (sqrtf(ss[m][q]) + 1e-8f);

  const bool hiz = (hi == 0);
  float num[4], psum[4];
  #pragma unroll
  for (int n = 0; n < 4; ++n) { num[n] = 0.f; psum[n] = 0.f; }

  #pragma unroll
  for (int m = 0; m < 3; ++m) {
    #pragma unroll
    for (int n = 0; n < 4; ++n) {
      bf16x4 pb;
      #pragma unroll
      for (int q = 0; q < 4; ++q) {
        float g = acc[m][n][q];
        float v = fmaxf(g, 0.1f * g);
        float p = exp2f(v * rinv[m][q]);
        if (m == 2) p = hiz ? p : 0.f;
        psum[n] += p;
        num[n] = fmaf(p, g, num[n]);
        pb[q] = (__bf16)p;
      }
      if (n < 3 || lo < 2)
        *(uint2*)&mybuf[(n * 16 + lo) * ASTR + m * 16 + hi * 4] =
            __builtin_bit_cast(uint2, pb);
    }
  }
  #pragma unroll
  for (int n = 0; n < 4; ++n) {
    num[n]  += __shfl_xor(num[n], 16);  num[n]  += __shfl_xor(num[n], 32);
    psum[n] += __shfl_xor(psum[n], 16); psum[n] += __shfl_xor(psum[n], 32);
  }
  WAVE_SYNC();

  bf16x8 gA[3][2];
  const u16* gp = gram_bf + (size_t)i * (RP * KP);
  #pragma unroll
  for (int m = 0; m < 3; ++m)
    #pragma unroll
    for (int kt = 0; kt < 2; ++kt)
      gA[m][kt] = __builtin_bit_cast(bf16x8,
          *(const uint4*)(gp + (m * 16 + lo) * KP + (kt << 5) + (hi << 3)));

  floatx4 tac[3][4];
  #pragma unroll
  for (int m = 0; m < 3; ++m)
    #pragma unroll
    for (int n = 0; n < 4; ++n) tac[m][n] = floatx4{0.f, 0.f, 0.f, 0.f};

  #pragma unroll
  for (int kt = 0; kt < 2; ++kt) {
    bf16x8 gB[4];
    #pragma unroll
    for (int n = 0; n < 4; ++n) {
      const uint2* bp = (const uint2*)&mybuf[(n * 16 + lo) * ASTR + (kt << 5) + (hi << 3)];
      uint2 b0 = bp[0], b1 = bp[1];
      uint4 bb; bb.x = b0.x; bb.y = b0.y; bb.z = b1.x; bb.w = b1.y;
      gB[n] = __builtin_bit_cast(bf16x8, bb);
    }
    #pragma unroll
    for (int m = 0; m < 3; ++m)
      #pragma unroll
      for (int n = 0; n < 4; ++n)
        tac[m][n] = __builtin_amdgcn_mfma_f32_16x16x32_bf16(gA[m][kt], gB[n], tac[m][n], 0, 0, 0);
  }

  float e4 = 0.f;
  #pragma unroll
  for (int n = 0; n < 4; ++n) {
    float w = 0.f;
    #pragma unroll
    for (int m = 0; m < 3; ++m) {
      uint2 av = *(const uint2*)&mybuf[(n * 16 + lo) * ASTR + m * 16 + hi * 4];
      w = fmaf(bflo(av.x), tac[m][n][0], w);
      w = fmaf(bfhi(av.x), tac[m][n][1], w);
      w = fmaf(bflo(av.y), tac[m][n][2], w);
      w = fmaf(bfhi(av.y), tac[m][n][3], w);
    }
    w += __shfl_xor(w, 16);
    w += __shfl_xor(w, 32);
    const int col = n * 16 + lo;
    if (col < len) {
      float inv = __builtin_amdgcn_rcpf(psum[n]);
      float wn2 = fmaxf(w * inv * inv, 0.f);
      float nm  = num[n] * inv;
      float den = fmaxf(sqrtf(wn2) * cn[j * LL + col], 1e-8f);
      float sim = nm * __builtin_amdgcn_rcpf(den);
      e4 += exp2f(sim * 8.656170245333781f);
    }
  }
  #pragma unroll
  for (int off = 1; off < 64; off <<= 1) e4 += __shfl_xor(e4, off);
  if (lane == 0)
    scores[i * NN + j] = (log2f(e4) - 2.0f) * 0.11552453009332421f;
}

// ---- loss: hinge terms vs diagonal, full reduction ------------------------
__global__ void loss_kernel(const float* __restrict__ sc, float* __restrict__ out) {
  __shared__ float diag[NN];
  __shared__ float wsum[4];
  const int t = threadIdx.x;
  diag[t] = sc[t * NN + t];
  __syncthreads();
  const float di = diag[t];
  const float4* row = (const float4*)(sc + t * NN);
  float acc = 0.f;
  for (int q = 0; q < 64; ++q) {
    float4 v = row[q];
    const int b = q * 4;
    if (b + 0 != t) acc += fmaxf(0.2f + v.x - di, 0.f) + fmaxf(0.2f + v.x - diag[b + 0], 0.f);
    if (b + 1 != t) acc += fmaxf(0.2f + v.y - di, 0.f) + fmaxf(0.2f + v.y - diag[b + 1], 0.f);
    if (b + 2 != t) acc += fmaxf(0.2f + v.z - di, 0.f) + fmaxf(0.2f + v.z - diag[b + 2], 0.f);
    if (b + 3 != t) acc += fmaxf(0.2f + v.w - di, 0.f) + fmaxf(0.2f + v.w - diag[b + 3], 0.f);
  }
  #pragma unroll
  for (int o = 32; o; o >>= 1) acc += __shfl_xor(acc, o);
  if ((t & 63) == 0) wsum[t >> 6] = acc;
  __syncthreads();
  if (t == 0) out[0] = wsum[0] + wsum[1] + wsum[2] + wsum[3];
}

// ---------------------------------------------------------------------------
extern "C" void kernel_launch(void* const* d_in, const int* in_sizes, int n_in,
                              void* d_out, int out_size, void* d_ws, size_t ws_size,
                              hipStream_t stream) {
  const float* im = (const float*)d_in[0];
  const float* s  = (const float*)d_in[1];
  const int* cap  = (const int*)d_in[2];
  float* out = (float*)d_out;

  char* ws = (char*)d_ws;
  u16*   im_bf   = (u16*)(ws);                         //  6,291,456 B
  u16*   s_bf    = (u16*)(ws + 6291456);               //  8,388,608 B
  u16*   gram_bf = (u16*)(ws + 14680064);              //  1,572,864 B
  float* cn      = (float*)(ws + 16252928);            //     51,200 B
  float* scores  = (float*)(ws + 16304128);            //    262,144 B

  prep_im_gram_kernel<<<dim3(NN), dim3(256), 0, stream>>>(im, im_bf, gram_bf);
  prep_s_kernel<<<dim3(NN), dim3(256), 0, stream>>>(s, s_bf, cn);
  xattn3_kernel<<<dim3(NN * 64), dim3(256), 0, stream>>>(im_bf, s_bf, gram_bf, cn, cap, scores);
  xattn4_kernel<<<dim3(NN * 64), dim3(256), 0, stream>>>(im_bf, s_bf, gram_bf, cn, cap, scores);
  loss_kernel<<<dim3(1), dim3(256), 0, stream>>>(scores, out);
}

// Round 9
// 527.869 us; speedup vs baseline: 1.3303x; 1.3303x over previous
//
#include <hip/hip_runtime.h>

// ---------------------------------------------------------------------------
// ContrastiveLoss (SCAN t2i cross-attention) on MI355X — round 9.
// N=256x256 pairs, R=36 regions, L=50 words, D=256.
// r9 vs r8: (1) xattn4 tail compacted via device-built long-caption list
// (grid 1024 blocks, grid-stride) instead of 16384 mostly-empty blocks;
// (2) preps fused into one 512-block kernel; (3) xattn3 hoists Gram loads
// above the softmax (latency hidden under VALU; fits 102-reg cap at nv=3).
// ---------------------------------------------------------------------------

typedef unsigned short u16;
typedef unsigned int u32;

typedef __attribute__((ext_vector_type(8))) __bf16 bf16x8;
typedef __attribute__((ext_vector_type(4))) __bf16 bf16x4;
typedef __attribute__((ext_vector_type(4))) float floatx4;

#define NN 256
#define RR 36
#define LL 50
#define DD 256
#define RP 48    // padded region dim
#define LP 64    // padded word dim (s rows)
#define KP 64    // gram row stride / matvec K
#define ASTR 68  // u16 stride of LDS rows
#define WROWS 50 // logical LDS rows per wave
#define SLOP 14  // shared overflow rows
#define PSTR 264 // u16 stride for prep LDS stage

__device__ __forceinline__ u16 f2bf(float v) {
  u32 u = __builtin_bit_cast(u32, v);
  u += 0x7fffu + ((u >> 16) & 1u);   // RNE (inputs never NaN)
  return (u16)(u >> 16);
}
__device__ __forceinline__ float bflo(u32 w) { return __builtin_bit_cast(float, w << 16); }
__device__ __forceinline__ float bfhi(u32 w) { return __builtin_bit_cast(float, w & 0xffff0000u); }

#define WAVE_SYNC() do { \
  asm volatile("s_waitcnt lgkmcnt(0)" ::: "memory"); \
  __builtin_amdgcn_sched_barrier(0); \
} while (0)

// ---- fused prep: blocks 0..255 im+gram; blocks 256..511 s+cn+longlist -----
__global__ void prep_kernel(const float* __restrict__ im,
                            const float* __restrict__ s,
                            const int* __restrict__ cap,
                            u16* __restrict__ im_bf,
                            u16* __restrict__ gram_bf,
                            u16* __restrict__ s_bf,
                            float* __restrict__ cn,
                            int* __restrict__ longcnt,
                            int* __restrict__ longlist) {
  __shared__ u16 Lb[RP * PSTR];
  const int t = threadIdx.x;
  if (blockIdx.x < NN) {
    // ---------------- im -> bf16 [48][256]; Gram -> bf16 [48][64] ----------
    const int i = blockIdx.x;
    const float* src = im + (size_t)i * (RR * DD);
    u16* dst = im_bf + (size_t)i * (RP * DD);
    for (int e = t; e < RR * DD; e += 256) {
      int r = e >> 8, d = e & 255;
      u16 b = f2bf(src[e]);
      dst[e] = b;
      Lb[r * PSTR + d] = b;
    }
    for (int e = RR * DD + t; e < RP * DD; e += 256) {
      int r = e >> 8, d = e & 255;
      dst[e] = 0;
      Lb[r * PSTR + d] = 0;
    }
    __syncthreads();
    if (t >= 64) return;   // wave 0 computes Gram via MFMA from LDS
    const int lane = t;
    const int lo = lane & 15, hi = lane >> 4;
    floatx4 acc[3][3];
    #pragma unroll
    for (int m = 0; m < 3; ++m)
      #pragma unroll
      for (int n = 0; n < 3; ++n) acc[m][n] = floatx4{0.f, 0.f, 0.f, 0.f};
    #pragma unroll 2
    for (int kt = 0; kt < 8; ++kt) {
      const int k0 = (kt << 5) + (hi << 3);
      bf16x8 f[3];
      #pragma unroll
      for (int m = 0; m < 3; ++m)
        f[m] = __builtin_bit_cast(bf16x8, *(const uint4*)&Lb[(m * 16 + lo) * PSTR + k0]);
      #pragma unroll
      for (int m = 0; m < 3; ++m)
        #pragma unroll
        for (int n = 0; n < 3; ++n)
          acc[m][n] = __builtin_amdgcn_mfma_f32_16x16x32_bf16(f[m], f[n], acc[m][n], 0, 0, 0);
    }
    u16* g = gram_bf + (size_t)i * (RP * KP);
    #pragma unroll
    for (int m = 0; m < 3; ++m)
      #pragma unroll
      for (int n = 0; n < 3; ++n)
        #pragma unroll
        for (int q = 0; q < 4; ++q)
          g[(m * 16 + hi * 4 + q) * KP + n * 16 + lo] = f2bf(acc[m][n][q]);
    for (int e = lane; e < RP * 16; e += 64) {
      int r = e >> 4, c = e & 15;
      g[r * KP + 48 + c] = 0;
    }
  } else {
    // ---------------- s -> bf16 [64][256]; cn; long-caption list ----------
    const int j = blockIdx.x - NN;
    const float* src = s + (size_t)j * (LL * DD);
    u16* dst = s_bf + (size_t)j * (LP * DD);
    for (int e = t; e < LL * DD; e += 256) dst[e] = f2bf(src[e]);
    for (int e = LL * DD + t; e < LP * DD; e += 256) dst[e] = 0;
    const int l = t >> 2, q = t & 3;
    float acc = 0.f;
    if (l < LL) {
      const float* row = src + l * DD + q * 64;
      #pragma unroll 4
      for (int d = 0; d < 64; ++d) { float v = row[d]; acc = fmaf(v, v, acc); }
    }
    acc += __shfl_xor(acc, 1);
    acc += __shfl_xor(acc, 2);
    if (l < LL && q == 0) cn[j * LL + l] = sqrtf(acc);
    if (t == 0 && cap[j] > 48) {
      int k = atomicAdd(longcnt, 1);
      longlist[k] = j;
    }
  }
}

// ---- xattn3: len<=48 pairs (nv=3 compile-time), 5 blocks/CU ---------------
__global__ __launch_bounds__(256, 5) void xattn3_kernel(
    const u16* __restrict__ im_bf, const u16* __restrict__ s_bf,
    const u16* __restrict__ gram_bf, const float* __restrict__ cn,
    const int* __restrict__ cap, float* __restrict__ scores) {
  __shared__ u16 buf[(4 * WROWS + SLOP) * ASTR];  // 29,104 B

  const int wid  = threadIdx.x >> 6;
  const int lane = threadIdx.x & 63;
  const int lo = lane & 15, hi = lane >> 4;
  const int i = blockIdx.x >> 6;
  const int j = ((blockIdx.x & 63) << 2) | wid;
  const int len = cap[j];
  if (len > 48) return;                 // handled by xattn4

  u16* mybuf = buf + wid * (WROWS * ASTR);

  // zero cols 48..63 of row `lane` (K-pad for matvec kt=1)
  if (lane < WROWS) {
    uint2 z2 = {0u, 0u};
    uint2* zp = (uint2*)&mybuf[lane * ASTR + 48];
    zp[0] = z2; zp[1] = z2; zp[2] = z2; zp[3] = z2;
  }

  // ---- Phase A: G = im_i @ s_j^T (M=48, N=48, K=256) ----------------------
  floatx4 acc[3][3];
  #pragma unroll
  for (int m = 0; m < 3; ++m)
    #pragma unroll
    for (int n = 0; n < 3; ++n) acc[m][n] = floatx4{0.f, 0.f, 0.f, 0.f};

  const u16* imp = im_bf + (size_t)i * (RP * DD);
  const u16* sp  = s_bf  + (size_t)j * (LP * DD);

  #pragma unroll 2
  for (int kt = 0; kt < 8; ++kt) {
    const int k0 = (kt << 5) + (hi << 3);
    bf16x8 af[3], bfr[3];
    #pragma unroll
    for (int m = 0; m < 3; ++m)
      af[m] = __builtin_bit_cast(bf16x8, *(const uint4*)(imp + (m * 16 + lo) * DD + k0));
    #pragma unroll
    for (int n = 0; n < 3; ++n)
      bfr[n] = __builtin_bit_cast(bf16x8, *(const uint4*)(sp + (n * 16 + lo) * DD + k0));
    #pragma unroll
    for (int m = 0; m < 3; ++m)
      #pragma unroll
      for (int n = 0; n < 3; ++n)
        acc[m][n] = __builtin_amdgcn_mfma_f32_16x16x32_bf16(af[m], bfr[n], acc[m][n], 0, 0, 0);
  }

  // ---- Gram A-fragments: hoisted HERE (nv=3 liveness fits 102 cap).
  // ~400cy L2 latency hides under the softmax VALU below.
  bf16x8 gA[3][2];
  const u16* gp = gram_bf + (size_t)i * (RP * KP);
  #pragma unroll
  for (int m = 0; m < 3; ++m)
    #pragma unroll
    for (int kt = 0; kt < 2; ++kt)
      gA[m][kt] = __builtin_bit_cast(bf16x8,
          *(const uint4*)(gp + (m * 16 + lo) * KP + (kt << 5) + (hi << 3)));

  // ---- In-fragment row norms: ss[m][q] = sum_{valid cols} leaky(G)^2 ------
  float maskf[3];
  #pragma unroll
  for (int n = 0; n < 3; ++n) maskf[n] = (n * 16 + lo < len) ? 1.f : 0.f;

  float ss[3][4];
  #pragma unroll
  for (int m = 0; m < 3; ++m)
    #pragma unroll
    for (int q = 0; q < 4; ++q) ss[m][q] = 0.f;
  #pragma unroll
  for (int m = 0; m < 3; ++m)
    #pragma unroll
    for (int n = 0; n < 3; ++n)
      #pragma unroll
      for (int q = 0; q < 4; ++q) {
        float g = acc[m][n][q];
        float v = fmaxf(g, 0.1f * g);
        ss[m][q] = fmaf(v * v, maskf[n], ss[m][q]);
      }
  #pragma unroll
  for (int off = 1; off < 16; off <<= 1)
    #pragma unroll
    for (int m = 0; m < 3; ++m)
      #pragma unroll
      for (int q = 0; q < 4; ++q)
        ss[m][q] += __shfl_xor(ss[m][q], off);

  float rinv[3][4];
  #pragma unroll
  for (int m = 0; m < 3; ++m)
    #pragma unroll
    for (int q = 0; q < 4; ++q)
      rinv[m][q] = 12.984255368000671f / (sqrtf(ss[m][q]) + 1e-8f); // 9*log2e/(||.||+eps)

  // ---- In-fragment softmax weights + num/psum partials; p -> LDS [l][r] ---
  const bool hiz = (hi == 0);
  float num[3], psum[3];
  #pragma unroll
  for (int n = 0; n < 3; ++n) { num[n] = 0.f; psum[n] = 0.f; }

  #pragma unroll
  for (int m = 0; m < 3; ++m) {
    #pragma unroll
    for (int n = 0; n < 3; ++n) {
      bf16x4 pb;
      #pragma unroll
      for (int q = 0; q < 4; ++q) {
        float g = acc[m][n][q];
        float v = fmaxf(g, 0.1f * g);
        float p = exp2f(v * rinv[m][q]);   // |arg|<=13 for valid cols
        if (m == 2) p = hiz ? p : 0.f;     // zero pad-rows 36..47
        psum[n] += p;
        num[n] = fmaf(p, g, num[n]);
        pb[q] = (__bf16)p;
      }
      *(uint2*)&mybuf[(n * 16 + lo) * ASTR + m * 16 + hi * 4] =
          __builtin_bit_cast(uint2, pb);
    }
  }
  #pragma unroll
  for (int n = 0; n < 3; ++n) {
    num[n]  += __shfl_xor(num[n], 16);  num[n]  += __shfl_xor(num[n], 32);
    psum[n] += __shfl_xor(psum[n], 16); psum[n] += __shfl_xor(psum[n], 32);
  }
  WAVE_SYNC();

  // ---- matvec: t = Gram_i @ p  (M=48, N=48, K=64 zero-padded) -------------
  floatx4 tac[3][3];
  #pragma unroll
  for (int m = 0; m < 3; ++m)
    #pragma unroll
    for (int n = 0; n < 3; ++n) tac[m][n] = floatx4{0.f, 0.f, 0.f, 0.f};

  #pragma unroll
  for (int kt = 0; kt < 2; ++kt) {
    bf16x8 gB[3];
    #pragma unroll
    for (int n = 0; n < 3; ++n) {
      const uint2* bp = (const uint2*)&mybuf[(n * 16 + lo) * ASTR + (kt << 5) + (hi << 3)];
      uint2 b0 = bp[0], b1 = bp[1];
      uint4 bb; bb.x = b0.x; bb.y = b0.y; bb.z = b1.x; bb.w = b1.y;
      gB[n] = __builtin_bit_cast(bf16x8, bb);
    }
    #pragma unroll
    for (int m = 0; m < 3; ++m)
      #pragma unroll
      for (int n = 0; n < 3; ++n)
        tac[m][n] = __builtin_amdgcn_mfma_f32_16x16x32_bf16(gA[m][kt], gB[n], tac[m][n], 0, 0, 0);
  }

  // ---- wn2 = sum_r p*t per column + finalize + max-free LSE ---------------
  float e4 = 0.f;
  #pragma unroll
  for (int n = 0; n < 3; ++n) {
    float w = 0.f;
    #pragma unroll
    for (int m = 0; m < 3; ++m) {
      uint2 av = *(const uint2*)&mybuf[(n * 16 + lo) * ASTR + m * 16 + hi * 4];
      w = fmaf(bflo(av.x), tac[m][n][0], w);
      w = fmaf(bfhi(av.x), tac[m][n][1], w);
      w = fmaf(bflo(av.y), tac[m][n][2], w);
      w = fmaf(bfhi(av.y), tac[m][n][3], w);
    }
    w += __shfl_xor(w, 16);
    w += __shfl_xor(w, 32);     // all hi-duplicates hold full sum over r
    const int col = n * 16 + lo;
    if (col < len) {
      float inv = __builtin_amdgcn_rcpf(psum[n]);
      float wn2 = fmaxf(w * inv * inv, 0.f);
      float nm  = num[n] * inv;
      float den = fmaxf(sqrtf(wn2) * cn[j * LL + col], 1e-8f);
      float sim = nm * __builtin_amdgcn_rcpf(den);
      e4 += exp2f(sim * 8.656170245333781f);   // 6*log2e; |arg| ~<= 9
    }
  }
  #pragma unroll
  for (int off = 1; off < 64; off <<= 1) e4 += __shfl_xor(e4, off);
  if (lane == 0)
    scores[i * NN + j] = (log2f(e4) - 2.0f) * 0.11552453009332421f; // ln2/6
}

// ---- xattn4: len>48 pairs, COMPACT launch (grid-stride over list) ---------
__global__ __launch_bounds__(256, 4) void xattn4_kernel(
    const u16* __restrict__ im_bf, const u16* __restrict__ s_bf,
    const u16* __restrict__ gram_bf, const float* __restrict__ cn,
    const int* __restrict__ cap, float* __restrict__ scores,
    const int* __restrict__ longcnt, const int* __restrict__ longlist) {
  __shared__ u16 buf[(4 * WROWS + SLOP) * ASTR];

  const int wid  = threadIdx.x >> 6;
  const int lane = threadIdx.x & 63;
  const int lo = lane & 15, hi = lane >> 4;
  const int nlong = longcnt[0];
  const int nitems = nlong << 8;        // 256 images per long caption
  u16* mybuf = buf + wid * (WROWS * ASTR);

  // zero cols 48..63 of row `lane` once (never overwritten by p-writes)
  if (lane < WROWS) {
    uint2 z2 = {0u, 0u};
    uint2* zp = (uint2*)&mybuf[lane * ASTR + 48];
    zp[0] = z2; zp[1] = z2; zp[2] = z2; zp[3] = z2;
  }

  for (int item = (blockIdx.x << 2) | wid; item < nitems; item += 4096) {
    const int i = item & 255;
    const int j = longlist[item >> 8];
    const int len = cap[j];

    floatx4 acc[3][4];
    #pragma unroll
    for (int m = 0; m < 3; ++m)
      #pragma unroll
      for (int n = 0; n < 4; ++n) acc[m][n] = floatx4{0.f, 0.f, 0.f, 0.f};

    const u16* imp = im_bf + (size_t)i * (RP * DD);
    const u16* sp  = s_bf  + (size_t)j * (LP * DD);

    #pragma unroll 2
    for (int kt = 0; kt < 8; ++kt) {
      const int k0 = (kt << 5) + (hi << 3);
      bf16x8 af[3], bfr[4];
      #pragma unroll
      for (int m = 0; m < 3; ++m)
        af[m] = __builtin_bit_cast(bf16x8, *(const uint4*)(imp + (m * 16 + lo) * DD + k0));
      #pragma unroll
      for (int n = 0; n < 4; ++n)
        bfr[n] = __builtin_bit_cast(bf16x8, *(const uint4*)(sp + (n * 16 + lo) * DD + k0));
      #pragma unroll
      for (int m = 0; m < 3; ++m)
        #pragma unroll
        for (int n = 0; n < 4; ++n)
          acc[m][n] = __builtin_amdgcn_mfma_f32_16x16x32_bf16(af[m], bfr[n], acc[m][n], 0, 0, 0);
    }

    float maskf[4];
    #pragma unroll
    for (int n = 0; n < 4; ++n) maskf[n] = (n * 16 + lo < len) ? 1.f : 0.f;

    float ss[3][4];
    #pragma unroll
    for (int m = 0; m < 3; ++m)
      #pragma unroll
      for (int q = 0; q < 4; ++q) ss[m][q] = 0.f;
    #pragma unroll
    for (int m = 0; m < 3; ++m)
      #pragma unroll
      for (int n = 0; n < 4; ++n)
        #pragma unroll
        for (int q = 0; q < 4; ++q) {
          float g = acc[m][n][q];
          float v = fmaxf(g, 0.1f * g);
          ss[m][q] = fmaf(v * v, maskf[n], ss[m][q]);
        }
    #pragma unroll
    for (int off = 1; off < 16; off <<= 1)
      #pragma unroll
      for (int m = 0; m < 3; ++m)
        #pragma unroll
        for (int q = 0; q < 4; ++q)
          ss[m][q] += __shfl_xor(ss[m][q], off);

    float rinv[3][4];
    #pragma unroll
    for (int m = 0; m < 3; ++m)
      #pragma unroll
      for (int q = 0; q < 4; ++q)
        rinv[m][q] = 12.984255368000671f / (sqrtf(ss[m][q]) + 1e-8f);

    const bool hiz = (hi == 0);
    float num[4], psum[4];
    #pragma unroll
    for (int n = 0; n < 4; ++n) { num[n] = 0.f; psum[n] = 0.f; }

    #pragma unroll
    for (int m = 0; m < 3; ++m) {
      #pragma unroll
      for (int n = 0; n < 4; ++n) {
        bf16x4 pb;
        #pragma unroll
        for (int q = 0; q < 4; ++q) {
          float g = acc[m][n][q];
          float v = fmaxf(g, 0.1f * g);
          float p = exp2f(v * rinv[m][q]);
          if (m == 2) p = hiz ? p : 0.f;
          psum[n] += p;
          num[n] = fmaf(p, g, num[n]);
          pb[q] = (__bf16)p;
        }
        if (n < 3 || lo < 2)
          *(uint2*)&mybuf[(n * 16 + lo) * ASTR + m * 16 + hi * 4] =
              __builtin_bit_cast(uint2, pb);
      }
    }
    #pragma unroll
    for (int n = 0; n < 4; ++n) {
      num[n]  += __shfl_xor(num[n], 16);  num[n]  += __shfl_xor(num[n], 32);
      psum[n] += __shfl_xor(psum[n], 16); psum[n] += __shfl_xor(psum[n], 32);
    }
    WAVE_SYNC();

    bf16x8 gA[3][2];
    const u16* gp = gram_bf + (size_t)i * (RP * KP);
    #pragma unroll
    for (int m = 0; m < 3; ++m)
      #pragma unroll
      for (int kt = 0; kt < 2; ++kt)
        gA[m][kt] = __builtin_bit_cast(bf16x8,
            *(const uint4*)(gp + (m * 16 + lo) * KP + (kt << 5) + (hi << 3)));

    floatx4 tac[3][4];
    #pragma unroll
    for (int m = 0; m < 3; ++m)
      #pragma unroll
      for (int n = 0; n < 4; ++n) tac[m][n] = floatx4{0.f, 0.f, 0.f, 0.f};

    #pragma unroll
    for (int kt = 0; kt < 2; ++kt) {
      bf16x8 gB[4];
      #pragma unroll
      for (int n = 0; n < 4; ++n) {
        const uint2* bp = (const uint2*)&mybuf[(n * 16 + lo) * ASTR + (kt << 5) + (hi << 3)];
        uint2 b0 = bp[0], b1 = bp[1];
        uint4 bb; bb.x = b0.x; bb.y = b0.y; bb.z = b1.x; bb.w = b1.y;
        gB[n] = __builtin_bit_cast(bf16x8, bb);
      }
      #pragma unroll
      for (int m = 0; m < 3; ++m)
        #pragma unroll
        for (int n = 0; n < 4; ++n)
          tac[m][n] = __builtin_amdgcn_mfma_f32_16x16x32_bf16(gA[m][kt], gB[n], tac[m][n], 0, 0, 0);
    }

    float e4 = 0.f;
    #pragma unroll
    for (int n = 0; n < 4; ++n) {
      float w = 0.f;
      #pragma unroll
      for (int m = 0; m < 3; ++m) {
        uint2 av = *(const uint2*)&mybuf[(n * 16 + lo) * ASTR + m * 16 + hi * 4];
        w = fmaf(bflo(av.x), tac[m][n][0], w);
        w = fmaf(bfhi(av.x), tac[m][n][1], w);
        w = fmaf(bflo(av.y), tac[m][n][2], w);
        w = fmaf(bfhi(av.y), tac[m][n][3], w);
      }
      w += __shfl_xor(w, 16);
      w += __shfl_xor(w, 32);
      const int col = n * 16 + lo;
      if (col < len) {
        float inv = __builtin_amdgcn_rcpf(psum[n]);
        float wn2 = fmaxf(w * inv * inv, 0.f);
        float nm  = num[n] * inv;
        float den = fmaxf(sqrtf(wn2) * cn[j * LL + col], 1e-8f);
        float sim = nm * __builtin_amdgcn_rcpf(den);
        e4 += exp2f(sim * 8.656170245333781f);
      }
    }
    #pragma unroll
    for (int off = 1; off < 64; off <<= 1) e4 += __shfl_xor(e4, off);
    if (lane == 0)
      scores[i * NN + j] = (log2f(e4) - 2.0f) * 0.11552453009332421f;
    WAVE_SYNC();   // drain LDS reads before next item overwrites mybuf
  }
}

// ---- loss: hinge terms vs diagonal, full reduction ------------------------
__global__ void loss_kernel(const float* __restrict__ sc, float* __restrict__ out) {
  __shared__ float diag[NN];
  __shared__ float wsum[4];
  const int t = threadIdx.x;
  diag[t] = sc[t * NN + t];
  __syncthreads();
  const float di = diag[t];
  const float4* row = (const float4*)(sc + t * NN);
  float acc = 0.f;
  for (int q = 0; q < 64; ++q) {
    float4 v = row[q];
    const int b = q * 4;
    if (b + 0 != t) acc += fmaxf(0.2f + v.x - di, 0.f) + fmaxf(0.2f + v.x - diag[b + 0], 0.f);
    if (b + 1 != t) acc += fmaxf(0.2f + v.y - di, 0.f) + fmaxf(0.2f + v.y - diag[b + 1], 0.f);
    if (b + 2 != t) acc += fmaxf(0.2f + v.z - di, 0.f) + fmaxf(0.2f + v.z - diag[b + 2], 0.f);
    if (b + 3 != t) acc += fmaxf(0.2f + v.w - di, 0.f) + fmaxf(0.2f + v.w - diag[b + 3], 0.f);
  }
  #pragma unroll
  for (int o = 32; o; o >>= 1) acc += __shfl_xor(acc, o);
  if ((t & 63) == 0) wsum[t >> 6] = acc;
  __syncthreads();
  if (t == 0) out[0] = wsum[0] + wsum[1] + wsum[2] + wsum[3];
}

// ---------------------------------------------------------------------------
extern "C" void kernel_launch(void* const* d_in, const int* in_sizes, int n_in,
                              void* d_out, int out_size, void* d_ws, size_t ws_size,
                              hipStream_t stream) {
  const float* im = (const float*)d_in[0];
  const float* s  = (const float*)d_in[1];
  const int* cap  = (const int*)d_in[2];
  float* out = (float*)d_out;

  char* ws = (char*)d_ws;
  u16*   im_bf   = (u16*)(ws);                         //  6,291,456 B
  u16*   s_bf    = (u16*)(ws + 6291456);               //  8,388,608 B
  u16*   gram_bf = (u16*)(ws + 14680064);              //  1,572,864 B
  float* cn      = (float*)(ws + 16252928);            //     51,200 B
  float* scores  = (float*)(ws + 16304128);            //    262,144 B
  int*   longcnt = (int*)(ws + 16566272);              //          4 B
  int*   longlst = (int*)(ws + 16566276);              //      1,024 B

  hipMemsetAsync(longcnt, 0, 4, stream);
  prep_kernel<<<dim3(2 * NN), dim3(256), 0, stream>>>(im, s, cap, im_bf, gram_bf,
                                                      s_bf, cn, longcnt, longlst);
  xattn3_kernel<<<dim3(NN * 64), dim3(256), 0, stream>>>(im_bf, s_bf, gram_bf, cn, cap, scores);
  xattn4_kernel<<<dim3(1024), dim3(256), 0, stream>>>(im_bf, s_bf, gram_bf, cn, cap, scores,
                                                      longcnt, longlst);
  loss_kernel<<<dim3(1), dim3(256), 0, stream>>>(scores, out);
}